// Round 1
// baseline (853.651 us; speedup 1.0000x reference)
//
#include <hip/hip_runtime.h>
#include <hip/hip_bf16.h>

#define DEVINL __device__ __forceinline__

typedef __attribute__((ext_vector_type(8))) short bf16x8;
typedef __attribute__((ext_vector_type(4))) float f32x4;

static constexpr int C   = 128;
static constexpr int SS  = 12288;  // S = NKV
static constexpr int NPQ = 16;
static constexpr int NH  = 9;
static constexpr int SB  = 4;          // s-units per block
static constexpr int ROWS = SB * NPQ;  // 64 rows per block

DEVINL unsigned short f2bf(float f) {
  __hip_bfloat16 h = __float2bfloat16(f);
  return __builtin_bit_cast(unsigned short, h);
}
DEVINL float bf2f(unsigned short u) {
  unsigned int v = ((unsigned int)u) << 16;
  return __builtin_bit_cast(float, v);
}
// XOR-swizzled element offset into a [64][128] bf16 LDS tile.
// 16B chunk index ^= (row&7): a-fragment ds_read_b128 across 16 rows at a
// fixed k-chunk spreads over 8 chunk slots = all 32 banks (T2 pattern).
DEVINL int swzoff(int r, int c) {
  return (r << 7) + ((((c >> 3) ^ (r & 7))) << 3) + (c & 7);
}
DEVINL float gelu_f(float x) {  // tanh-approximate gelu (jax default)
  float u = 0.7978845608028654f * (x + 0.044715f * x * x * x);
  float t = 1.0f - 2.0f / (__expf(2.0f * u) + 1.0f);
  return 0.5f * x * (1.0f + t);
}

// ---------------------------------------------------------------------------
// Kernel 0: repack six 128x128 fp32 weights into bf16 MFMA-B-fragment order.
// Fragment flat index f = (((kt*8 + nt)*64 + lane)*8 + i)
//   holds W[kt*32 + (lane>>4)*8 + i][nt*16 + (lane&15)]
// so kernel2's per-wave b-fragment load is one coalesced 16B read per lane.
// ---------------------------------------------------------------------------
__global__ void prep_weights(const float* __restrict__ w0, const float* __restrict__ w1,
                             const float* __restrict__ w2, const float* __restrict__ w3,
                             const float* __restrict__ w4, const float* __restrict__ w5,
                             unsigned short* __restrict__ wfrag) {
  int gid = blockIdx.x * 256 + threadIdx.x;   // < 6*16384
  int widx = gid >> 14, f = gid & 16383;
  const float* W = (widx == 0) ? w0 : (widx == 1) ? w1 : (widx == 2) ? w2
                 : (widx == 3) ? w3 : (widx == 4) ? w4 : w5;
  int i = f & 7, l = (f >> 3) & 63, nt = (f >> 9) & 7, kt = f >> 12;
  int k = kt * 32 + (l >> 4) * 8 + i;
  int n = nt * 16 + (l & 15);
  wfrag[gid] = f2bf(W[k * 128 + n]);
}

// ---------------------------------------------------------------------------
// Kernel 1: kv = LN(x_kv) @ Wkv + bkv  -> bf16 workspace (2*12288 x 256)
// ---------------------------------------------------------------------------
__global__ __launch_bounds__(256) void kv_proj(
    const float* __restrict__ xkv, const float* __restrict__ lns,
    const float* __restrict__ lnb, const float* __restrict__ Wkv,
    const float* __restrict__ bkv, unsigned short* __restrict__ kvout) {
  __shared__ float y[16][132];   // +4 pad: fp32 rows, float4 broadcast reads
  const int tid = threadIdx.x;
  const size_t rb = (size_t)blockIdx.x * 16;

  {  // stage + LN: 16 threads per row, 8 channels each
    int r = tid >> 4, p = tid & 15;
    const float* xr = xkv + (rb + r) * C + p * 8;
    float v[8];
    float sum = 0.f, sq = 0.f;
#pragma unroll
    for (int i = 0; i < 2; ++i) {
      float4 q4 = *(const float4*)(xr + i * 4);
      v[i * 4 + 0] = q4.x; v[i * 4 + 1] = q4.y; v[i * 4 + 2] = q4.z; v[i * 4 + 3] = q4.w;
      sum += q4.x + q4.y + q4.z + q4.w;
      sq  += q4.x * q4.x + q4.y * q4.y + q4.z * q4.z + q4.w * q4.w;
    }
    sum += __shfl_xor(sum, 1, 16); sum += __shfl_xor(sum, 2, 16);
    sum += __shfl_xor(sum, 4, 16); sum += __shfl_xor(sum, 8, 16);
    sq  += __shfl_xor(sq, 1, 16);  sq  += __shfl_xor(sq, 2, 16);
    sq  += __shfl_xor(sq, 4, 16);  sq  += __shfl_xor(sq, 8, 16);
    float mu = sum * (1.0f / 128.f);
    float rs = rsqrtf(sq * (1.0f / 128.f) - mu * mu + 1e-5f);
#pragma unroll
    for (int i = 0; i < 8; ++i) {
      int c = p * 8 + i;
      y[r][c] = (v[i] - mu) * rs * lns[c] + lnb[c];
    }
  }
  __syncthreads();

  const int c2 = tid;  // 256 output columns
  float acc[16];
#pragma unroll
  for (int r = 0; r < 16; ++r) acc[r] = 0.f;
  for (int c = 0; c < 128; c += 4) {
    float w0 = Wkv[(c + 0) * 256 + c2];
    float w1 = Wkv[(c + 1) * 256 + c2];
    float w2 = Wkv[(c + 2) * 256 + c2];
    float w3 = Wkv[(c + 3) * 256 + c2];
#pragma unroll
    for (int r = 0; r < 16; ++r) {
      float4 yv = *(const float4*)&y[r][c];
      acc[r] += yv.x * w0 + yv.y * w1 + yv.z * w2 + yv.w * w3;
    }
  }
  float bb = bkv[c2];
#pragma unroll
  for (int r = 0; r < 16; ++r)
    kvout[(rb + r) * 256 + c2] = f2bf(acc[r] + bb);
}

// ---------------------------------------------------------------------------
// mm64: 64x128 = (64x128 bf16 LDS) @ (128x128 weight frags), MFMA 16x16x32.
// 4 waves, wave w owns n-tiles {2w,2w+1} x all 4 m-tiles (8 tiles, 32 MFMA).
// A and B both loaded with identical lane->k maps => any HW k-permutation
// cancels. MODE 0: +bias -> dst LDS. MODE 1: +bias, gelu -> dst.
// MODE 2: final: m=acc+b2; out = xq + gamma*o + gmlp*m -> global.
// ---------------------------------------------------------------------------
template <int MODE>
DEVINL void mm64(const unsigned short* src, unsigned short* dst,
                 const unsigned short* __restrict__ wf,
                 const float* __restrict__ bias,
                 const unsigned short* obuf, const float* __restrict__ xqb,
                 float* __restrict__ outb, const float* __restrict__ gamma,
                 const float* __restrict__ gmlp, int tid) {
  const int l = tid & 63, wv = tid >> 6;
  const int lo = l & 15, g = l >> 4;

  bf16x8 bfr[4][2];
#pragma unroll
  for (int kt = 0; kt < 4; ++kt)
#pragma unroll
    for (int j = 0; j < 2; ++j) {
      int nt = wv * 2 + j;
      bfr[kt][j] = *(const bf16x8*)(wf + (((kt * 8 + nt) * 64 + l) << 3));
    }

  f32x4 acc[4][2];
#pragma unroll
  for (int m = 0; m < 4; ++m)
#pragma unroll
    for (int j = 0; j < 2; ++j) acc[m][j] = (f32x4){0.f, 0.f, 0.f, 0.f};

#pragma unroll
  for (int kt = 0; kt < 4; ++kt) {
    bf16x8 a[4];
#pragma unroll
    for (int m = 0; m < 4; ++m)
      a[m] = *(const bf16x8*)(src + swzoff(m * 16 + lo, kt * 32 + g * 8));
#pragma unroll
    for (int m = 0; m < 4; ++m)
#pragma unroll
      for (int j = 0; j < 2; ++j)
        acc[m][j] = __builtin_amdgcn_mfma_f32_16x16x32_bf16(a[m], bfr[kt][j],
                                                            acc[m][j], 0, 0, 0);
  }

#pragma unroll
  for (int j = 0; j < 2; ++j) {
    int col = (wv * 2 + j) * 16 + lo;
    float bv = bias ? bias[col] : 0.0f;
    float gm = (MODE == 2) ? gamma[col] : 0.0f;
    float gp = (MODE == 2) ? gmlp[col] : 0.0f;
#pragma unroll
    for (int m = 0; m < 4; ++m) {
#pragma unroll
      for (int e = 0; e < 4; ++e) {
        int row = m * 16 + g * 4 + e;   // C/D: col=lane&15, row=(lane>>4)*4+e
        float v = acc[m][j][e] + bv;
        if (MODE == 1) v = gelu_f(v);
        if (MODE == 2) {
          float ov = bf2f(obuf[swzoff(row, col)]);
          float xv = xqb[row * C + col] + gm * ov;  // x_q re-read: L2-hot
          outb[row * C + col] = xv + gp * v;
        } else {
          dst[swzoff(row, col)] = f2bf(v);
        }
      }
    }
  }
}

// ---------------------------------------------------------------------------
// Kernel 2: fused main. One block = 4 s-units = 64 q-rows.
// ---------------------------------------------------------------------------
__global__ __launch_bounds__(256) void fused_main(
    const float* __restrict__ xq, const int* __restrict__ nh_idx,
    const unsigned char* __restrict__ nh_mask,
    const unsigned short* __restrict__ wfrag,
    const unsigned short* __restrict__ kvws,
    const float* __restrict__ ln_q_s, const float* __restrict__ ln_q_b,
    const float* __restrict__ bq, const float* __restrict__ b_out,
    const float* __restrict__ gamma, const float* __restrict__ ln_m_s,
    const float* __restrict__ ln_m_b, const float* __restrict__ bm,
    const float* __restrict__ b1, const float* __restrict__ b2,
    const float* __restrict__ gmlp, float* __restrict__ out) {
  __shared__ __align__(16) unsigned short bufA[ROWS * C];
  __shared__ __align__(16) unsigned short bufB[ROWS * C];
  __shared__ __align__(16) unsigned short bufC[ROWS * C];
  __shared__ __align__(16) unsigned short kvb[NH * 256];
  __shared__ float sc[4][16][12];
  __shared__ float biasn[NH];

  const int tid = threadIdx.x;
  const int bid = blockIdx.x;
  const int t  = bid / (SS / SB);
  const int s0 = (bid % (SS / SB)) * SB;
  const float* xqb = xq + ((size_t)(t * SS + s0)) * NPQ * C;  // 64x128 slab
  float* outb = out + ((size_t)(t * SS + s0)) * NPQ * C;

  // ---- stage + LN1 -> bufA (bf16, swizzled). 4 threads/row, 32 ch each.
  {
    int r = tid >> 2, p = tid & 3;
    const float* xr = xqb + r * C + p * 32;
    float v[32];
    float sum = 0.f, sq = 0.f;
#pragma unroll
    for (int i = 0; i < 8; ++i) {
      float4 q4 = *(const float4*)(xr + i * 4);
      v[i * 4 + 0] = q4.x; v[i * 4 + 1] = q4.y; v[i * 4 + 2] = q4.z; v[i * 4 + 3] = q4.w;
      sum += q4.x + q4.y + q4.z + q4.w;
      sq  += q4.x * q4.x + q4.y * q4.y + q4.z * q4.z + q4.w * q4.w;
    }
    sum += __shfl_xor(sum, 1, 4); sum += __shfl_xor(sum, 2, 4);
    sq  += __shfl_xor(sq, 1, 4);  sq  += __shfl_xor(sq, 2, 4);
    float mu = sum * (1.0f / C);
    float rs = rsqrtf(sq * (1.0f / C) - mu * mu + 1e-5f);
#pragma unroll
    for (int cc = 0; cc < 4; ++cc) {
      unsigned short pk[8];
#pragma unroll
      for (int i = 0; i < 8; ++i) {
        int c = p * 32 + cc * 8 + i;
        pk[i] = f2bf((v[cc * 8 + i] - mu) * rs * ln_q_s[c] + ln_q_b[c]);
      }
      *(uint4*)&bufA[swzoff(r, p * 32 + cc * 8)] = *(const uint4*)pk;
    }
  }
  __syncthreads();

  // q = y @ Wq + bq  (A->B)
  mm64<0>(bufA, bufB, wfrag + 0 * 16384, bq, nullptr, nullptr, nullptr, nullptr, nullptr, tid);
  __syncthreads();
  // qh = q @ Wa_q    (B->A)
  mm64<0>(bufB, bufA, wfrag + 1 * 16384, nullptr, nullptr, nullptr, nullptr, nullptr, nullptr, tid);
  __syncthreads();

  // ---- attention per s-unit: scores -> softmax -> PV, ao rows into bufB
  for (int su = 0; su < SB; ++su) {
    int s = s0 + su;
    if (su) __syncthreads();  // protect kvb/sc rewrite vs previous PV reads
    if (tid < NH) biasn[tid] = nh_mask[s * NH + tid] ? 0.0f : -1e9f;
    for (int idx = tid; idx < NH * 128; idx += 256) {  // gather 9 kv rows (bf16 pairs)
      int n = idx >> 7, cp = idx & 127;
      int jrow = nh_idx[s * NH + n];
      unsigned int u = ((const unsigned int*)kvws)[((size_t)t * SS + jrow) * 128 + cp];
      int c = cp * 2;
      int off = (n << 8) + ((((c >> 3) ^ (n & 7))) << 3) + (c & 7);
      *(unsigned int*)&kvb[off] = u;
    }
    __syncthreads();
    // scores: 576 = 4h * 16q * 9n items
    for (int it = tid; it < 576; it += 256) {
      int n = it % 9, hq = it / 9;
      int h = hq >> 4, qi = hq & 15;
      float a = 0.f;
#pragma unroll
      for (int dc = 0; dc < 4; ++dc) {
        int cq = h * 32 + dc * 8;
        bf16x8 qv = *(const bf16x8*)&bufA[swzoff(su * 16 + qi, cq)];
        int koff = (n << 8) + ((((cq >> 3) ^ (n & 7))) << 3);
        bf16x8 kv8 = *(const bf16x8*)&kvb[koff];
#pragma unroll
        for (int e = 0; e < 8; ++e)
          a += bf2f((unsigned short)qv[e]) * bf2f((unsigned short)kv8[e]);
      }
      sc[h][qi][n] = a * 0.17677669529663687f + biasn[n];  // 1/sqrt(32)
    }
    __syncthreads();
    if (tid < 64) {  // softmax over n=9
      int h = tid >> 4, qi = tid & 15;
      float mx = sc[h][qi][0];
#pragma unroll
      for (int n = 1; n < 9; ++n) mx = fmaxf(mx, sc[h][qi][n]);
      float e[9], ssum = 0.f;
#pragma unroll
      for (int n = 0; n < 9; ++n) { e[n] = __expf(sc[h][qi][n] - mx); ssum += e[n]; }
      float inv = 1.0f / ssum;
#pragma unroll
      for (int n = 0; n < 9; ++n) sc[h][qi][n] = e[n] * inv;
    }
    __syncthreads();
    {  // PV: thread -> (qi, 8-col chunk)
      int qi = tid >> 4, ck = tid & 15;
      int c = ck * 8, h = c >> 5;
      float o8[8];
#pragma unroll
      for (int e = 0; e < 8; ++e) o8[e] = 0.f;
#pragma unroll
      for (int n = 0; n < 9; ++n) {
        float a = sc[h][qi][n];
        int voff = (n << 8) + (((((128 + c) >> 3) ^ (n & 7))) << 3);
        bf16x8 vv = *(const bf16x8*)&kvb[voff];
#pragma unroll
        for (int e = 0; e < 8; ++e) o8[e] += a * bf2f((unsigned short)vv[e]);
      }
      unsigned short pk[8];
#pragma unroll
      for (int e = 0; e < 8; ++e) pk[e] = f2bf(o8[e]);
      *(uint4*)&bufB[swzoff(su * 16 + qi, c)] = *(const uint4*)pk;
    }
  }
  __syncthreads();

  // o = ao @ W_out + b_out  (B->C); C stays live until the final epilogue
  mm64<0>(bufB, bufC, wfrag + 2 * 16384, b_out, nullptr, nullptr, nullptr, nullptr, nullptr, tid);
  __syncthreads();

  // ---- x = xq + gamma*o; LN2 -> bufB
  {
    int r = tid >> 2, p = tid & 3;
    const float* xr = xqb + r * C + p * 32;
    float v[32];
    float sum = 0.f, sq = 0.f;
#pragma unroll
    for (int cc = 0; cc < 4; ++cc) {
      int c0 = p * 32 + cc * 8;
      uint4 ou = *(const uint4*)&bufC[swzoff(r, c0)];
      const unsigned short* op = (const unsigned short*)&ou;
#pragma unroll
      for (int i = 0; i < 8; ++i) {
        int c = c0 + i;
        float xv = xr[cc * 8 + i] + gamma[c] * bf2f(op[i]);
        v[cc * 8 + i] = xv;
        sum += xv; sq += xv * xv;
      }
    }
    sum += __shfl_xor(sum, 1, 4); sum += __shfl_xor(sum, 2, 4);
    sq  += __shfl_xor(sq, 1, 4);  sq  += __shfl_xor(sq, 2, 4);
    float mu = sum * (1.0f / C);
    float rs = rsqrtf(sq * (1.0f / C) - mu * mu + 1e-5f);
#pragma unroll
    for (int cc = 0; cc < 4; ++cc) {
      unsigned short pk[8];
#pragma unroll
      for (int i = 0; i < 8; ++i) {
        int c = p * 32 + cc * 8 + i;
        pk[i] = f2bf((v[cc * 8 + i] - mu) * rs * ln_m_s[c] + ln_m_b[c]);
      }
      *(uint4*)&bufB[swzoff(r, p * 32 + cc * 8)] = *(const uint4*)pk;
    }
  }
  __syncthreads();

  // h1 = y2 @ Wm + bm      (B->A)
  mm64<0>(bufB, bufA, wfrag + 3 * 16384, bm, nullptr, nullptr, nullptr, nullptr, nullptr, tid);
  __syncthreads();
  // g = gelu(h1 @ W1 + b1) (A->B)
  mm64<1>(bufA, bufB, wfrag + 4 * 16384, b1, nullptr, nullptr, nullptr, nullptr, nullptr, tid);
  __syncthreads();
  // m = g @ W2 + b2; out = xq + gamma*o + gmlp*m  (B->global)
  mm64<2>(bufB, nullptr, wfrag + 5 * 16384, b2, bufC, xqb, outb, gamma, gmlp, tid);
}

// ---------------------------------------------------------------------------
extern "C" void kernel_launch(void* const* d_in, const int* in_sizes, int n_in,
                              void* d_out, int out_size, void* d_ws, size_t ws_size,
                              hipStream_t stream) {
  const float* x_q     = (const float*)d_in[0];
  const float* x_kv    = (const float*)d_in[1];
  const int* nh_idx    = (const int*)d_in[2];
  const unsigned char* nh_mask = (const unsigned char*)d_in[3];  // numpy bool_
  const float* ln_q_s  = (const float*)d_in[4];
  const float* ln_q_b  = (const float*)d_in[5];
  const float* Wq      = (const float*)d_in[6];
  const float* bq      = (const float*)d_in[7];
  const float* ln_kv_s = (const float*)d_in[8];
  const float* ln_kv_b = (const float*)d_in[9];
  const float* Wkv     = (const float*)d_in[10];
  const float* bkv     = (const float*)d_in[11];
  const float* Wa_q    = (const float*)d_in[12];
  const float* W_out   = (const float*)d_in[13];
  const float* b_out   = (const float*)d_in[14];
  const float* gamma   = (const float*)d_in[15];
  const float* ln_m_s  = (const float*)d_in[16];
  const float* ln_m_b  = (const float*)d_in[17];
  const float* Wm      = (const float*)d_in[18];
  const float* bm      = (const float*)d_in[19];
  const float* W1      = (const float*)d_in[20];
  const float* b1      = (const float*)d_in[21];
  const float* W2      = (const float*)d_in[22];
  const float* b2      = (const float*)d_in[23];
  const float* gmlp    = (const float*)d_in[24];

  // ws layout: [0] 6*16384 bf16 weight frags (192 KB); then kv bf16 (12.6 MB)
  unsigned short* wfrag = (unsigned short*)d_ws;
  unsigned short* kvws  = wfrag + 6 * 16384;

  prep_weights<<<384, 256, 0, stream>>>(Wq, Wa_q, W_out, Wm, W1, W2, wfrag);
  kv_proj<<<1536, 256, 0, stream>>>(x_kv, ln_kv_s, ln_kv_b, Wkv, bkv, kvws);
  fused_main<<<6144, 256, 0, stream>>>(x_q, nh_idx, nh_mask, wfrag, kvws,
                                       ln_q_s, ln_q_b, bq, b_out, gamma,
                                       ln_m_s, ln_m_b, bm, b1, b2, gmlp,
                                       (float*)d_out);
}

// Round 2
// 565.368 us; speedup vs baseline: 1.5099x; 1.5099x over previous
//
#include <hip/hip_runtime.h>
#include <hip/hip_bf16.h>

#define DEVINL __device__ __forceinline__

typedef __attribute__((ext_vector_type(8))) short bf16x8;
typedef __attribute__((ext_vector_type(4))) float f32x4;

static constexpr int C   = 128;
static constexpr int SS  = 12288;  // S = NKV
static constexpr int NPQ = 16;
static constexpr int NH  = 9;

DEVINL unsigned short f2bf(float f) {
  __hip_bfloat16 h = __float2bfloat16(f);
  return __builtin_bit_cast(unsigned short, h);
}
DEVINL float bf2f(unsigned short u) {
  unsigned int v = ((unsigned int)u) << 16;
  return __builtin_bit_cast(float, v);
}
// XOR-swizzled element offset into a [16][128] bf16 LDS tile (16B chunk ^= row&7).
DEVINL int swz(int r, int c) {
  return (r << 7) + ((((c >> 3) ^ (r & 7))) << 3) + (c & 7);
}
// Intra-wave LDS producer->consumer fence (no __syncthreads needed: all
// producers/consumers are lanes of the same wave; drain LDS queue + forbid
// compiler reordering across the phase boundary).
DEVINL void wave_sync() { asm volatile("s_waitcnt lgkmcnt(0)" ::: "memory"); }

DEVINL float gelu_f(float x) {  // tanh-approximate gelu (jax default)
  float u = 0.7978845608028654f * (x + 0.044715f * x * x * x);
  float t = 1.0f - 2.0f / (__expf(2.0f * u) + 1.0f);
  return 0.5f * x * (1.0f + t);
}

// ---------------------------------------------------------------------------
// Kernel 0: repack six 128x128 fp32 weights into bf16 MFMA-B-fragment order.
// f = (((kt*8 + nt)*64 + lane)*8 + i) holds W[kt*32 + (lane>>4)*8 + i][nt*16 + (lane&15)]
// ---------------------------------------------------------------------------
__global__ void prep_weights(const float* __restrict__ w0, const float* __restrict__ w1,
                             const float* __restrict__ w2, const float* __restrict__ w3,
                             const float* __restrict__ w4, const float* __restrict__ w5,
                             unsigned short* __restrict__ wfrag) {
  int gid = blockIdx.x * 256 + threadIdx.x;   // < 6*16384
  int widx = gid >> 14, f = gid & 16383;
  const float* W = (widx == 0) ? w0 : (widx == 1) ? w1 : (widx == 2) ? w2
                 : (widx == 3) ? w3 : (widx == 4) ? w4 : w5;
  int i = f & 7, l = (f >> 3) & 63, nt = (f >> 9) & 7, kt = f >> 12;
  int k = kt * 32 + (l >> 4) * 8 + i;
  int n = nt * 16 + (l & 15);
  wfrag[gid] = f2bf(W[k * 128 + n]);
}

// ---------------------------------------------------------------------------
// Kernel 1: kv = LN(x_kv) @ Wkv + bkv  -> bf16 workspace (2*12288 x 256)
// ---------------------------------------------------------------------------
__global__ __launch_bounds__(256) void kv_proj(
    const float* __restrict__ xkv, const float* __restrict__ lns,
    const float* __restrict__ lnb, const float* __restrict__ Wkv,
    const float* __restrict__ bkv, unsigned short* __restrict__ kvout) {
  __shared__ float y[16][132];
  const int tid = threadIdx.x;
  const size_t rb = (size_t)blockIdx.x * 16;

  {
    int r = tid >> 4, p = tid & 15;
    const float* xr = xkv + (rb + r) * C + p * 8;
    float v[8];
    float sum = 0.f, sq = 0.f;
#pragma unroll
    for (int i = 0; i < 2; ++i) {
      float4 q4 = *(const float4*)(xr + i * 4);
      v[i * 4 + 0] = q4.x; v[i * 4 + 1] = q4.y; v[i * 4 + 2] = q4.z; v[i * 4 + 3] = q4.w;
      sum += q4.x + q4.y + q4.z + q4.w;
      sq  += q4.x * q4.x + q4.y * q4.y + q4.z * q4.z + q4.w * q4.w;
    }
    sum += __shfl_xor(sum, 1, 16); sum += __shfl_xor(sum, 2, 16);
    sum += __shfl_xor(sum, 4, 16); sum += __shfl_xor(sum, 8, 16);
    sq  += __shfl_xor(sq, 1, 16);  sq  += __shfl_xor(sq, 2, 16);
    sq  += __shfl_xor(sq, 4, 16);  sq  += __shfl_xor(sq, 8, 16);
    float mu = sum * (1.0f / 128.f);
    float rs = rsqrtf(sq * (1.0f / 128.f) - mu * mu + 1e-5f);
#pragma unroll
    for (int i = 0; i < 8; ++i) {
      int c = p * 8 + i;
      y[r][c] = (v[i] - mu) * rs * lns[c] + lnb[c];
    }
  }
  __syncthreads();

  const int c2 = tid;
  float acc[16];
#pragma unroll
  for (int r = 0; r < 16; ++r) acc[r] = 0.f;
  for (int c = 0; c < 128; c += 4) {
    float w0 = Wkv[(c + 0) * 256 + c2];
    float w1 = Wkv[(c + 1) * 256 + c2];
    float w2 = Wkv[(c + 2) * 256 + c2];
    float w3 = Wkv[(c + 3) * 256 + c2];
#pragma unroll
    for (int r = 0; r < 16; ++r) {
      float4 yv = *(const float4*)&y[r][c];
      acc[r] += yv.x * w0 + yv.y * w1 + yv.z * w2 + yv.w * w3;
    }
  }
  float bb = bkv[c2];
#pragma unroll
  for (int r = 0; r < 16; ++r)
    kvout[(rb + r) * 256 + c2] = f2bf(acc[r] + bb);
}

// ---------------------------------------------------------------------------
// mm16: per-wave 16x128 = (16x128 bf16 LDS) @ (128x128 weight frags).
// 1 m-tile x 8 n-tiles x 4 kt = 32 MFMA. A and B use identical lane->k maps.
// MODE 0: dst = bf16(acc + bias). MODE 1: + gelu.
// MODE 2: dst = bf16( xq[row][col] + gamma[col] * (acc + bias) )   (x2 build)
// ---------------------------------------------------------------------------
template <int MODE>
DEVINL void mm16(const unsigned short* src, unsigned short* dst,
                 const unsigned short* __restrict__ wf,
                 const float* __restrict__ bias,
                 const float* __restrict__ xqw, const float* __restrict__ gamma,
                 int l) {
  const int lo = l & 15, g = l >> 4;
  f32x4 acc[8];
#pragma unroll
  for (int nt = 0; nt < 8; ++nt) acc[nt] = (f32x4){0.f, 0.f, 0.f, 0.f};

#pragma unroll
  for (int kt = 0; kt < 4; ++kt) {
    bf16x8 a = *(const bf16x8*)(src + swz(lo, kt * 32 + g * 8));
#pragma unroll
    for (int nt = 0; nt < 8; ++nt) {
      bf16x8 b = *(const bf16x8*)(wf + (((kt * 8 + nt) * 64 + l) << 3));
      acc[nt] = __builtin_amdgcn_mfma_f32_16x16x32_bf16(a, b, acc[nt], 0, 0, 0);
    }
  }

#pragma unroll
  for (int nt = 0; nt < 8; ++nt) {
    int col = nt * 16 + lo;
    float bv = bias ? bias[col] : 0.0f;
    float gm = (MODE == 2) ? gamma[col] : 0.0f;
#pragma unroll
    for (int e = 0; e < 4; ++e) {
      int row = g * 4 + e;   // C/D: col=lane&15, row=(lane>>4)*4+e
      float v = acc[nt][e] + bv;
      if (MODE == 1) v = gelu_f(v);
      if (MODE == 2) v = xqw[row * C + col] + gm * v;
      dst[swz(row, col)] = f2bf(v);
    }
  }
}

// ---------------------------------------------------------------------------
// Kernel 2: fused main, wave-autonomous. One wave = one s-unit = 16 rows.
// Zero __syncthreads; intra-wave lgkmcnt fences only.
// ---------------------------------------------------------------------------
__global__ __launch_bounds__(256, 3) void fused_main(
    const float* __restrict__ xq, const int* __restrict__ nh_idx,
    const unsigned char* __restrict__ nh_mask,
    const unsigned short* __restrict__ wfrag,
    const unsigned short* __restrict__ kvws,
    const float* __restrict__ ln_q_s, const float* __restrict__ ln_q_b,
    const float* __restrict__ bq, const float* __restrict__ b_out,
    const float* __restrict__ gamma, const float* __restrict__ ln_m_s,
    const float* __restrict__ ln_m_b, const float* __restrict__ bm,
    const float* __restrict__ b1, const float* __restrict__ b2,
    const float* __restrict__ gmlp, float* __restrict__ out) {
  __shared__ __align__(16) unsigned short Ab[4][2048];
  __shared__ __align__(16) unsigned short Bb[4][2048];
  __shared__ __align__(16) unsigned short Kb[4][2304];  // kv gather; later x2

  const int tid = threadIdx.x, l = tid & 63, wv = tid >> 6;
  const int bid = blockIdx.x;
  const int t = bid / (SS / 4);
  const int s = (bid % (SS / 4)) * 4 + wv;
  const float* xqw = xq + (size_t)(t * SS + s) * NPQ * C;
  float* outw = out + (size_t)(t * SS + s) * NPQ * C;
  unsigned short* A = Ab[wv];
  unsigned short* B = Bb[wv];
  unsigned short* K = Kb[wv];

  // ---- P0: issue kv gather early (T14: load now, LDS-write later)
  int jr[9]; float bn[9];
#pragma unroll
  for (int n = 0; n < 9; ++n) {
    jr[n] = nh_idx[s * 9 + n];
    bn[n] = nh_mask[s * 9 + n] ? 0.0f : -1e9f;
  }
  uint4 gr[5];
#pragma unroll
  for (int i = 0; i < 5; ++i) {
    int idx = l + i * 64;           // 288 = 9 rows x 32 chunks of 8 bf16
    if (idx < 288) {
      int n = idx >> 5, ch = idx & 31;
      gr[i] = *(const uint4*)(kvws + ((size_t)(t * SS + jr[n]) * 256) + ch * 8);
    }
  }

  // ---- P1: LN1 of own 16 rows -> A (bf16 swizzled). 4 lanes/row, 32 ch each.
  {
    int r = l >> 2, p = l & 3;
    const float* xr = xqw + r * C + p * 32;
    float v[32];
    float sum = 0.f, sq = 0.f;
#pragma unroll
    for (int i = 0; i < 8; ++i) {
      float4 q4 = *(const float4*)(xr + i * 4);
      v[i * 4 + 0] = q4.x; v[i * 4 + 1] = q4.y; v[i * 4 + 2] = q4.z; v[i * 4 + 3] = q4.w;
      sum += q4.x + q4.y + q4.z + q4.w;
      sq  += q4.x * q4.x + q4.y * q4.y + q4.z * q4.z + q4.w * q4.w;
    }
    sum += __shfl_xor(sum, 1, 4); sum += __shfl_xor(sum, 2, 4);
    sq  += __shfl_xor(sq, 1, 4);  sq  += __shfl_xor(sq, 2, 4);
    float mu = sum * (1.0f / C);
    float rs = rsqrtf(sq * (1.0f / C) - mu * mu + 1e-5f);
#pragma unroll
    for (int cc = 0; cc < 4; ++cc) {
      unsigned short pk[8];
#pragma unroll
      for (int i = 0; i < 8; ++i) {
        int c = p * 32 + cc * 8 + i;
        pk[i] = f2bf((v[cc * 8 + i] - mu) * rs * ln_q_s[c] + ln_q_b[c]);
      }
      *(uint4*)&A[swz(r, p * 32 + cc * 8)] = *(const uint4*)pk;
    }
  }
  // ---- P1.5: land the kv gather into K ([9][256] linear bf16)
#pragma unroll
  for (int i = 0; i < 5; ++i) {
    int idx = l + i * 64;
    if (idx < 288) *(uint4*)(K + idx * 8) = gr[i];
  }
  wave_sync();

  // q = y1 @ Wq + bq   (A->B)
  mm16<0>(A, B, wfrag + 0 * 16384, bq, nullptr, nullptr, l);
  wave_sync();
  // qh = q @ Wa_q      (B->A)
  mm16<0>(B, A, wfrag + 1 * 16384, nullptr, nullptr, nullptr, l);
  wave_sync();

  // ---- attention, fully per-lane: lane = (h, qi)
  {
    const int h = l >> 4, qi = l & 15;
    float qf[32];
#pragma unroll
    for (int dc = 0; dc < 4; ++dc) {
      bf16x8 qv = *(const bf16x8*)(A + swz(qi, h * 32 + dc * 8));
#pragma unroll
      for (int e = 0; e < 8; ++e) qf[dc * 8 + e] = bf2f((unsigned short)qv[e]);
    }
    float sn[9];
#pragma unroll
    for (int n = 0; n < 9; ++n) {
      float a = 0.f;
#pragma unroll
      for (int dc = 0; dc < 4; ++dc) {
        bf16x8 k8 = *(const bf16x8*)(K + n * 256 + h * 32 + dc * 8);
#pragma unroll
        for (int e = 0; e < 8; ++e) a += qf[dc * 8 + e] * bf2f((unsigned short)k8[e]);
      }
      sn[n] = a * 0.17677669529663687f + bn[n];  // 1/sqrt(32)
    }
    float mx = sn[0];
#pragma unroll
    for (int n = 1; n < 9; ++n) mx = fmaxf(mx, sn[n]);
    float ssum = 0.f;
#pragma unroll
    for (int n = 0; n < 9; ++n) { sn[n] = __expf(sn[n] - mx); ssum += sn[n]; }
    float inv = 1.0f / ssum;
    float o32[32];
#pragma unroll
    for (int j = 0; j < 32; ++j) o32[j] = 0.f;
#pragma unroll
    for (int n = 0; n < 9; ++n) {
      float a = sn[n] * inv;
#pragma unroll
      for (int dc = 0; dc < 4; ++dc) {
        bf16x8 v8 = *(const bf16x8*)(K + n * 256 + 128 + h * 32 + dc * 8);
#pragma unroll
        for (int e = 0; e < 8; ++e) o32[dc * 8 + e] += a * bf2f((unsigned short)v8[e]);
      }
    }
#pragma unroll
    for (int dc = 0; dc < 4; ++dc) {
      unsigned short pk[8];
#pragma unroll
      for (int e = 0; e < 8; ++e) pk[e] = f2bf(o32[dc * 8 + e]);
      *(uint4*)(B + swz(qi, h * 32 + dc * 8)) = *(const uint4*)pk;
    }
  }
  wave_sync();

  // x2 = xq + gamma*(ao @ W_out + b_out)   (B -> K, K's gather data is dead)
  mm16<2>(B, K, wfrag + 2 * 16384, b_out, xqw, gamma, l);
  wave_sync();

  // ---- LN2: K (x2 bf16) -> A (y2)
  {
    int r = l >> 2, p = l & 3;
    float v[32];
    float sum = 0.f, sq = 0.f;
#pragma unroll
    for (int cc = 0; cc < 4; ++cc) {
      uint4 u = *(const uint4*)(K + swz(r, p * 32 + cc * 8));
      const unsigned short* up = (const unsigned short*)&u;
#pragma unroll
      for (int i = 0; i < 8; ++i) {
        float xv = bf2f(up[i]);
        v[cc * 8 + i] = xv;
        sum += xv; sq += xv * xv;
      }
    }
    sum += __shfl_xor(sum, 1, 4); sum += __shfl_xor(sum, 2, 4);
    sq  += __shfl_xor(sq, 1, 4);  sq  += __shfl_xor(sq, 2, 4);
    float mu = sum * (1.0f / C);
    float rs = rsqrtf(sq * (1.0f / C) - mu * mu + 1e-5f);
#pragma unroll
    for (int cc = 0; cc < 4; ++cc) {
      unsigned short pk[8];
#pragma unroll
      for (int i = 0; i < 8; ++i) {
        int c = p * 32 + cc * 8 + i;
        pk[i] = f2bf((v[cc * 8 + i] - mu) * rs * ln_m_s[c] + ln_m_b[c]);
      }
      *(uint4*)&A[swz(r, p * 32 + cc * 8)] = *(const uint4*)pk;
    }
  }
  wave_sync();

  // h1 = y2 @ Wm + bm        (A->B)
  mm16<0>(A, B, wfrag + 3 * 16384, bm, nullptr, nullptr, l);
  wave_sync();
  // g = gelu(h1 @ W1 + b1)   (B->A)
  mm16<1>(B, A, wfrag + 4 * 16384, b1, nullptr, nullptr, l);
  wave_sync();
  // m = g @ W2 + b2          (A->B)
  mm16<0>(A, B, wfrag + 5 * 16384, b2, nullptr, nullptr, l);
  wave_sync();

  // ---- store: out = x2 + gmlp*m, coalesced (2 rows / round, float4/lane)
  {
    int c4 = (l & 31) * 4;
    float4 gp4 = *(const float4*)(gmlp + c4);
#pragma unroll
    for (int rr = 0; rr < 8; ++rr) {
      int row = rr * 2 + (l >> 5);
      int off = swz(row, c4 & ~7) + (c4 & 7);  // c4&7 in {0,4}: within-chunk
      uint2 mu2 = *(const uint2*)(B + off);
      uint2 xu2 = *(const uint2*)(K + off);
      const unsigned short* mp = (const unsigned short*)&mu2;
      const unsigned short* xp = (const unsigned short*)&xu2;
      float4 ov;
      ov.x = bf2f(xp[0]) + gp4.x * bf2f(mp[0]);
      ov.y = bf2f(xp[1]) + gp4.y * bf2f(mp[1]);
      ov.z = bf2f(xp[2]) + gp4.z * bf2f(mp[2]);
      ov.w = bf2f(xp[3]) + gp4.w * bf2f(mp[3]);
      *(float4*)(outw + row * C + c4) = ov;
    }
  }
}

// ---------------------------------------------------------------------------
extern "C" void kernel_launch(void* const* d_in, const int* in_sizes, int n_in,
                              void* d_out, int out_size, void* d_ws, size_t ws_size,
                              hipStream_t stream) {
  const float* x_q     = (const float*)d_in[0];
  const float* x_kv    = (const float*)d_in[1];
  const int* nh_idx    = (const int*)d_in[2];
  const unsigned char* nh_mask = (const unsigned char*)d_in[3];
  const float* ln_q_s  = (const float*)d_in[4];
  const float* ln_q_b  = (const float*)d_in[5];
  const float* Wq      = (const float*)d_in[6];
  const float* bq      = (const float*)d_in[7];
  const float* ln_kv_s = (const float*)d_in[8];
  const float* ln_kv_b = (const float*)d_in[9];
  const float* Wkv     = (const float*)d_in[10];
  const float* bkv     = (const float*)d_in[11];
  const float* Wa_q    = (const float*)d_in[12];
  const float* W_out   = (const float*)d_in[13];
  const float* b_out   = (const float*)d_in[14];
  const float* gamma   = (const float*)d_in[15];
  const float* ln_m_s  = (const float*)d_in[16];
  const float* ln_m_b  = (const float*)d_in[17];
  const float* Wm      = (const float*)d_in[18];
  const float* bm      = (const float*)d_in[19];
  const float* W1      = (const float*)d_in[20];
  const float* b1      = (const float*)d_in[21];
  const float* W2      = (const float*)d_in[22];
  const float* b2      = (const float*)d_in[23];
  const float* gmlp    = (const float*)d_in[24];

  unsigned short* wfrag = (unsigned short*)d_ws;          // 192 KB
  unsigned short* kvws  = wfrag + 6 * 16384;              // 12.6 MB

  prep_weights<<<384, 256, 0, stream>>>(Wq, Wa_q, W_out, Wm, W1, W2, wfrag);
  kv_proj<<<1536, 256, 0, stream>>>(x_kv, ln_kv_s, ln_kv_b, Wkv, bkv, kvws);
  fused_main<<<6144, 256, 0, stream>>>(x_q, nh_idx, nh_mask, wfrag, kvws,
                                       ln_q_s, ln_q_b, bq, b_out, gamma,
                                       ln_m_s, ln_m_b, bm, b1, b2, gmlp,
                                       (float*)d_out);
}

// Round 3
// 506.373 us; speedup vs baseline: 1.6858x; 1.1165x over previous
//
#include <hip/hip_runtime.h>
#include <hip/hip_bf16.h>

#define DEVINL __device__ __forceinline__

typedef __attribute__((ext_vector_type(8))) short bf16x8;
typedef __attribute__((ext_vector_type(4))) float f32x4;

static constexpr int C   = 128;
static constexpr int SS  = 12288;  // S = NKV
static constexpr int NPQ = 16;

DEVINL unsigned short f2bf(float f) {
  __hip_bfloat16 h = __float2bfloat16(f);
  return __builtin_bit_cast(unsigned short, h);
}
DEVINL float bf2f(unsigned short u) {
  unsigned int v = ((unsigned int)u) << 16;
  return __builtin_bit_cast(float, v);
}
// XOR-swizzled element offset into a [16][128] bf16 LDS tile (16B chunk ^= row&7).
DEVINL int swz(int r, int c) {
  return (r << 7) + ((((c >> 3) ^ (r & 7))) << 3) + (c & 7);
}
// Intra-wave LDS producer->consumer fence (per-wave private buffers only).
DEVINL void wave_sync() { asm volatile("s_waitcnt lgkmcnt(0)" ::: "memory"); }

DEVINL float gelu_f(float x) {  // tanh-approximate gelu (jax default)
  float u = 0.7978845608028654f * (x + 0.044715f * x * x * x);
  float t = 1.0f - 2.0f / (__expf(2.0f * u) + 1.0f);
  return 0.5f * x * (1.0f + t);
}

// Cooperative 8KB weight-slice stage: global wfrag -> LDS slot, via
// global_load_lds width=16. slice = mi*4 + kt, contiguous 4096 bf16.
DEVINL void stage_slice(const unsigned short* __restrict__ wf_all,
                        unsigned short* Wslot, int slice, int tid) {
  const unsigned short* src = wf_all + (size_t)slice * 4096;
  const int wv = tid >> 6, l = tid & 63;
#pragma unroll
  for (int r = 0; r < 2; ++r) {
    int off = (r * 4 + wv) * 512;  // elements; wave-uniform LDS base
    __builtin_amdgcn_global_load_lds(
        (const __attribute__((address_space(1))) unsigned int*)(src + off + l * 8),
        (__attribute__((address_space(3))) unsigned int*)(Wslot + off),
        16, 0, 0);
  }
}

// ---------------------------------------------------------------------------
// Kernel 0: repack six 128x128 fp32 weights into bf16 MFMA-B-fragment order.
// f = (((kt*8 + nt)*64 + lane)*8 + i) holds W[kt*32 + (lane>>4)*8 + i][nt*16 + (lane&15)]
// ---------------------------------------------------------------------------
__global__ void prep_weights(const float* __restrict__ w0, const float* __restrict__ w1,
                             const float* __restrict__ w2, const float* __restrict__ w3,
                             const float* __restrict__ w4, const float* __restrict__ w5,
                             unsigned short* __restrict__ wfrag) {
  int gid = blockIdx.x * 256 + threadIdx.x;   // < 6*16384
  int widx = gid >> 14, f = gid & 16383;
  const float* W = (widx == 0) ? w0 : (widx == 1) ? w1 : (widx == 2) ? w2
                 : (widx == 3) ? w3 : (widx == 4) ? w4 : w5;
  int i = f & 7, l = (f >> 3) & 63, nt = (f >> 9) & 7, kt = f >> 12;
  int k = kt * 32 + (l >> 4) * 8 + i;
  int n = nt * 16 + (l & 15);
  wfrag[gid] = f2bf(W[k * 128 + n]);
}

// ---------------------------------------------------------------------------
// Kernel 1: kv = LN(x_kv) @ Wkv + bkv  -> bf16 workspace (12288 x 256)
// ---------------------------------------------------------------------------
__global__ __launch_bounds__(256) void kv_proj(
    const float* __restrict__ xkv, const float* __restrict__ lns,
    const float* __restrict__ lnb, const float* __restrict__ Wkv,
    const float* __restrict__ bkv, unsigned short* __restrict__ kvout) {
  __shared__ float y[16][132];
  const int tid = threadIdx.x;
  const size_t rb = (size_t)blockIdx.x * 16;

  {
    int r = tid >> 4, p = tid & 15;
    const float* xr = xkv + (rb + r) * C + p * 8;
    float v[8];
    float sum = 0.f, sq = 0.f;
#pragma unroll
    for (int i = 0; i < 2; ++i) {
      float4 q4 = *(const float4*)(xr + i * 4);
      v[i * 4 + 0] = q4.x; v[i * 4 + 1] = q4.y; v[i * 4 + 2] = q4.z; v[i * 4 + 3] = q4.w;
      sum += q4.x + q4.y + q4.z + q4.w;
      sq  += q4.x * q4.x + q4.y * q4.y + q4.z * q4.z + q4.w * q4.w;
    }
    sum += __shfl_xor(sum, 1, 16); sum += __shfl_xor(sum, 2, 16);
    sum += __shfl_xor(sum, 4, 16); sum += __shfl_xor(sum, 8, 16);
    sq  += __shfl_xor(sq, 1, 16);  sq  += __shfl_xor(sq, 2, 16);
    sq  += __shfl_xor(sq, 4, 16);  sq  += __shfl_xor(sq, 8, 16);
    float mu = sum * (1.0f / 128.f);
    float rs = rsqrtf(sq * (1.0f / 128.f) - mu * mu + 1e-5f);
#pragma unroll
    for (int i = 0; i < 8; ++i) {
      int c = p * 8 + i;
      y[r][c] = (v[i] - mu) * rs * lns[c] + lnb[c];
    }
  }
  __syncthreads();

  const int c2 = tid;
  float acc[16];
#pragma unroll
  for (int r = 0; r < 16; ++r) acc[r] = 0.f;
  for (int c = 0; c < 128; c += 4) {
    float w0 = Wkv[(c + 0) * 256 + c2];
    float w1 = Wkv[(c + 1) * 256 + c2];
    float w2 = Wkv[(c + 2) * 256 + c2];
    float w3 = Wkv[(c + 3) * 256 + c2];
#pragma unroll
    for (int r = 0; r < 16; ++r) {
      float4 yv = *(const float4*)&y[r][c];
      acc[r] += yv.x * w0 + yv.y * w1 + yv.z * w2 + yv.w * w3;
    }
  }
  float bb = bkv[c2];
#pragma unroll
  for (int r = 0; r < 16; ++r)
    kvout[(rb + r) * 256 + c2] = f2bf(acc[r] + bb);
}

// ---------------------------------------------------------------------------
// mm16_pipe: per-wave 16x128 @ 128x128, weights from LDS Wb ping-pong, with
// next-slice prefetch + per-kt __syncthreads (block-wide stage pipeline).
// MODE 0: dst = bf16(acc+bias). 1: +gelu. 2: dst = bf16(xq + gamma*(acc+bias)).
// MODE 3: out[row][col] = x2(K) + gmlp*(acc+bias), scalar global stores.
// ---------------------------------------------------------------------------
template <int MODE>
DEVINL void mm16_pipe(const unsigned short* src, unsigned short* dst,
                      unsigned short (*Wb)[4096],
                      const unsigned short* __restrict__ wf_all, int j0,
                      const float* __restrict__ bias,
                      const float* __restrict__ xqw,
                      const float* __restrict__ gamma,
                      const unsigned short* xK,
                      const float* __restrict__ gmlp,
                      float* __restrict__ outw, int tid) {
  const int l = tid & 63, lo = l & 15, g = l >> 4;
  f32x4 acc[8];
#pragma unroll
  for (int nt = 0; nt < 8; ++nt) acc[nt] = (f32x4){0.f, 0.f, 0.f, 0.f};

#pragma unroll
  for (int kt = 0; kt < 4; ++kt) {
    const int j = j0 + kt;
    if (j + 1 < 24) stage_slice(wf_all, Wb[(j + 1) & 1], j + 1, tid);
    const unsigned short* W = Wb[j & 1];
    bf16x8 a = *(const bf16x8*)(src + swz(lo, kt * 32 + g * 8));
#pragma unroll
    for (int nt = 0; nt < 8; ++nt) {
      bf16x8 b = *(const bf16x8*)(W + nt * 512 + l * 8);
      acc[nt] = __builtin_amdgcn_mfma_f32_16x16x32_bf16(a, b, acc[nt], 0, 0, 0);
    }
    __syncthreads();   // drains stage vmem + all waves done reading W[j&1]
  }

#pragma unroll
  for (int nt = 0; nt < 8; ++nt) {
    int col = nt * 16 + lo;
    float bv = bias ? bias[col] : 0.0f;
    float gm = (MODE == 2) ? gamma[col] : 0.0f;
    float gp = (MODE == 3) ? gmlp[col] : 0.0f;
#pragma unroll
    for (int e = 0; e < 4; ++e) {
      int row = g * 4 + e;   // C/D: col=lane&15, row=(lane>>4)*4+e
      float v = acc[nt][e] + bv;
      if (MODE == 1) v = gelu_f(v);
      if (MODE == 2) v = xqw[row * C + col] + gm * v;
      if (MODE == 3) {
        float x2 = bf2f(xK[swz(row, col)]);
        outw[row * C + col] = x2 + gp * v;   // scalar store (dense, R1-verified)
      } else {
        dst[swz(row, col)] = f2bf(v);
      }
    }
  }
}

// ---------------------------------------------------------------------------
// Kernel 2: fused main. Block = 4 waves x 1 s-unit; shared weight pipeline.
// ---------------------------------------------------------------------------
__global__ __launch_bounds__(256, 2) void fused_main(
    const float* __restrict__ xq, const int* __restrict__ nh_idx,
    const unsigned char* __restrict__ nh_mask,
    const unsigned short* __restrict__ wfrag,
    const unsigned short* __restrict__ kvws,
    const float* __restrict__ ln_q_s, const float* __restrict__ ln_q_b,
    const float* __restrict__ bq, const float* __restrict__ b_out,
    const float* __restrict__ gamma, const float* __restrict__ ln_m_s,
    const float* __restrict__ ln_m_b, const float* __restrict__ bm,
    const float* __restrict__ b1, const float* __restrict__ b2,
    const float* __restrict__ gmlp, float* __restrict__ out) {
  __shared__ __align__(16) unsigned short Wb[2][4096];   // 16 KB weight ping-pong
  __shared__ __align__(16) unsigned short Ab[4][2048];
  __shared__ __align__(16) unsigned short Bb[4][2048];
  __shared__ __align__(16) unsigned short Kb[4][2304];   // kv gather; later x2

  const int tid = threadIdx.x, l = tid & 63, wv = tid >> 6;
  const int bid = blockIdx.x;
  const int t = bid / (SS / 4);
  const int s = (bid % (SS / 4)) * 4 + wv;
  const float* xqw = xq + (size_t)(t * SS + s) * NPQ * C;
  float* outw = out + (size_t)(t * SS + s) * NPQ * C;
  unsigned short* A = Ab[wv];
  unsigned short* B = Bb[wv];
  unsigned short* K = Kb[wv];

  // ---- P0: stage first weight slice + kv gather direct-to-LDS
  stage_slice(wfrag, Wb[0], 0, tid);
  int jr[9]; float bn[9];
#pragma unroll
  for (int n = 0; n < 9; ++n) {
    jr[n] = nh_idx[s * 9 + n];
    bn[n] = nh_mask[s * 9 + n] ? 0.0f : -1e9f;
  }
#pragma unroll
  for (int r = 0; r < 5; ++r) {
    int idx = r * 64 + l;            // 288 = 9 rows x 32 chunks of 8 bf16
    if (idx < 288) {
      int n = idx >> 5, ch = idx & 31;
      __builtin_amdgcn_global_load_lds(
          (const __attribute__((address_space(1))) unsigned int*)
              (kvws + ((size_t)(t * SS + jr[n])) * 256 + ch * 8),
          (__attribute__((address_space(3))) unsigned int*)(K + r * 512),
          16, 0, 0);
    }
  }

  // ---- P1: LN1 of own 16 rows -> A. 4 lanes/row, 32 channels each.
  {
    int r = l >> 2, p = l & 3;
    const float* xr = xqw + r * C + p * 32;
    float v[32];
    float sum = 0.f, sq = 0.f;
#pragma unroll
    for (int i = 0; i < 8; ++i) {
      float4 q4 = *(const float4*)(xr + i * 4);
      v[i * 4 + 0] = q4.x; v[i * 4 + 1] = q4.y; v[i * 4 + 2] = q4.z; v[i * 4 + 3] = q4.w;
      sum += q4.x + q4.y + q4.z + q4.w;
      sq  += q4.x * q4.x + q4.y * q4.y + q4.z * q4.z + q4.w * q4.w;
    }
    sum += __shfl_xor(sum, 1, 4); sum += __shfl_xor(sum, 2, 4);
    sq  += __shfl_xor(sq, 1, 4);  sq  += __shfl_xor(sq, 2, 4);
    float mu = sum * (1.0f / C);
    float rs = rsqrtf(sq * (1.0f / C) - mu * mu + 1e-5f);
#pragma unroll
    for (int cc = 0; cc < 4; ++cc) {
      unsigned short pk[8];
#pragma unroll
      for (int i = 0; i < 8; ++i) {
        int c = p * 32 + cc * 8 + i;
        pk[i] = f2bf((v[cc * 8 + i] - mu) * rs * ln_q_s[c] + ln_q_b[c]);
      }
      *(uint4*)&A[swz(r, p * 32 + cc * 8)] = *(const uint4*)pk;
    }
  }
  __syncthreads();   // slice 0 + K gather + LN writes all visible

  // q = y1 @ Wq + bq     (A->B), slices 0..3
  mm16_pipe<0>(A, B, Wb, wfrag, 0, bq, nullptr, nullptr, nullptr, nullptr, nullptr, tid);
  wave_sync();
  // qh = q @ Wa_q        (B->A), slices 4..7
  mm16_pipe<0>(B, A, Wb, wfrag, 4, nullptr, nullptr, nullptr, nullptr, nullptr, nullptr, tid);
  wave_sync();

  // ---- attention, per-lane: lane = (h, qi). reads A(qh), K(kv); writes B(ao)
  {
    const int h = l >> 4, qi = l & 15;
    float qf[32];
#pragma unroll
    for (int dc = 0; dc < 4; ++dc) {
      bf16x8 qv = *(const bf16x8*)(A + swz(qi, h * 32 + dc * 8));
#pragma unroll
      for (int e = 0; e < 8; ++e) qf[dc * 8 + e] = bf2f((unsigned short)qv[e]);
    }
    float sn[9];
#pragma unroll
    for (int n = 0; n < 9; ++n) {
      float a = 0.f;
#pragma unroll
      for (int dc = 0; dc < 4; ++dc) {
        bf16x8 k8 = *(const bf16x8*)(K + n * 256 + h * 32 + dc * 8);
#pragma unroll
        for (int e = 0; e < 8; ++e) a += qf[dc * 8 + e] * bf2f((unsigned short)k8[e]);
      }
      sn[n] = a * 0.17677669529663687f + bn[n];  // 1/sqrt(32)
    }
    float mx = sn[0];
#pragma unroll
    for (int n = 1; n < 9; ++n) mx = fmaxf(mx, sn[n]);
    float ssum = 0.f;
#pragma unroll
    for (int n = 0; n < 9; ++n) { sn[n] = __expf(sn[n] - mx); ssum += sn[n]; }
    float inv = 1.0f / ssum;
    float o32[32];
#pragma unroll
    for (int j = 0; j < 32; ++j) o32[j] = 0.f;
#pragma unroll
    for (int n = 0; n < 9; ++n) {
      float a = sn[n] * inv;
#pragma unroll
      for (int dc = 0; dc < 4; ++dc) {
        bf16x8 v8 = *(const bf16x8*)(K + n * 256 + 128 + h * 32 + dc * 8);
#pragma unroll
        for (int e = 0; e < 8; ++e) o32[dc * 8 + e] += a * bf2f((unsigned short)v8[e]);
      }
    }
#pragma unroll
    for (int dc = 0; dc < 4; ++dc) {
      unsigned short pk[8];
#pragma unroll
      for (int e = 0; e < 8; ++e) pk[e] = f2bf(o32[dc * 8 + e]);
      *(uint4*)(B + swz(qi, h * 32 + dc * 8)) = *(const uint4*)pk;
    }
  }
  wave_sync();

  // x2 = xq + gamma*(ao @ W_out + b_out)  (B->K), slices 8..11
  mm16_pipe<2>(B, K, Wb, wfrag, 8, b_out, xqw, gamma, nullptr, nullptr, nullptr, tid);
  wave_sync();

  // ---- LN2: K (x2 bf16) -> A (y2); K keeps x2 for the final epilogue
  {
    int r = l >> 2, p = l & 3;
    float v[32];
    float sum = 0.f, sq = 0.f;
#pragma unroll
    for (int cc = 0; cc < 4; ++cc) {
      uint4 u = *(const uint4*)(K + swz(r, p * 32 + cc * 8));
      const unsigned short* up = (const unsigned short*)&u;
#pragma unroll
      for (int i = 0; i < 8; ++i) {
        float xv = bf2f(up[i]);
        v[cc * 8 + i] = xv;
        sum += xv; sq += xv * xv;
      }
    }
    sum += __shfl_xor(sum, 1, 4); sum += __shfl_xor(sum, 2, 4);
    sq  += __shfl_xor(sq, 1, 4);  sq  += __shfl_xor(sq, 2, 4);
    float mu = sum * (1.0f / C);
    float rs = rsqrtf(sq * (1.0f / C) - mu * mu + 1e-5f);
#pragma unroll
    for (int cc = 0; cc < 4; ++cc) {
      unsigned short pk[8];
#pragma unroll
      for (int i = 0; i < 8; ++i) {
        int c = p * 32 + cc * 8 + i;
        pk[i] = f2bf((v[cc * 8 + i] - mu) * rs * ln_m_s[c] + ln_m_b[c]);
      }
      *(uint4*)&A[swz(r, p * 32 + cc * 8)] = *(const uint4*)pk;
    }
  }
  wave_sync();

  // h1 = y2 @ Wm + bm        (A->B), slices 12..15
  mm16_pipe<0>(A, B, Wb, wfrag, 12, bm, nullptr, nullptr, nullptr, nullptr, nullptr, tid);
  wave_sync();
  // g = gelu(h1 @ W1 + b1)   (B->A), slices 16..19
  mm16_pipe<1>(B, A, Wb, wfrag, 16, b1, nullptr, nullptr, nullptr, nullptr, nullptr, tid);
  wave_sync();
  // m = g @ W2 + b2; out = x2 + gmlp*m   (A -> global), slices 20..23
  mm16_pipe<3>(A, nullptr, Wb, wfrag, 20, b2, nullptr, nullptr, K, gmlp, outw, tid);
}

// ---------------------------------------------------------------------------
extern "C" void kernel_launch(void* const* d_in, const int* in_sizes, int n_in,
                              void* d_out, int out_size, void* d_ws, size_t ws_size,
                              hipStream_t stream) {
  const float* x_q     = (const float*)d_in[0];
  const float* x_kv    = (const float*)d_in[1];
  const int* nh_idx    = (const int*)d_in[2];
  const unsigned char* nh_mask = (const unsigned char*)d_in[3];
  const float* ln_q_s  = (const float*)d_in[4];
  const float* ln_q_b  = (const float*)d_in[5];
  const float* Wq      = (const float*)d_in[6];
  const float* bq      = (const float*)d_in[7];
  const float* ln_kv_s = (const float*)d_in[8];
  const float* ln_kv_b = (const float*)d_in[9];
  const float* Wkv     = (const float*)d_in[10];
  const float* bkv     = (const float*)d_in[11];
  const float* Wa_q    = (const float*)d_in[12];
  const float* W_out   = (const float*)d_in[13];
  const float* b_out   = (const float*)d_in[14];
  const float* gamma   = (const float*)d_in[15];
  const float* ln_m_s  = (const float*)d_in[16];
  const float* ln_m_b  = (const float*)d_in[17];
  const float* Wm      = (const float*)d_in[18];
  const float* bm      = (const float*)d_in[19];
  const float* W1      = (const float*)d_in[20];
  const float* b1      = (const float*)d_in[21];
  const float* W2      = (const float*)d_in[22];
  const float* b2      = (const float*)d_in[23];
  const float* gmlp    = (const float*)d_in[24];

  unsigned short* wfrag = (unsigned short*)d_ws;          // 192 KB
  unsigned short* kvws  = wfrag + 6 * 16384;              // 12.6 MB

  prep_weights<<<384, 256, 0, stream>>>(Wq, Wa_q, W_out, Wm, W1, W2, wfrag);
  kv_proj<<<1536, 256, 0, stream>>>(x_kv, ln_kv_s, ln_kv_b, Wkv, bkv, kvws);
  fused_main<<<6144, 256, 0, stream>>>(x_q, nh_idx, nh_mask, wfrag, kvws,
                                       ln_q_s, ln_q_b, bq, b_out, gamma,
                                       ln_m_s, ln_m_b, bm, b1, b2, gmlp,
                                       (float*)d_out);
}

// Round 5
// 378.987 us; speedup vs baseline: 2.2525x; 1.3361x over previous
//
#include <hip/hip_runtime.h>
#include <hip/hip_bf16.h>

#define DEVINL __device__ __forceinline__

typedef __attribute__((ext_vector_type(8))) short bf16x8;
typedef __attribute__((ext_vector_type(4))) float f32x4;

static constexpr int C   = 128;
static constexpr int SS  = 12288;  // S = NKV
static constexpr int NPQ = 16;

DEVINL f32x4 mfma16(bf16x8 a, bf16x8 b, f32x4 c) {
  return __builtin_amdgcn_mfma_f32_16x16x32_bf16(a, b, c, 0, 0, 0);
}
DEVINL f32x4 f32x4_zero() { f32x4 z; z[0] = 0.f; z[1] = 0.f; z[2] = 0.f; z[3] = 0.f; return z; }

DEVINL unsigned short f2bf(float f) {
  __hip_bfloat16 h = __float2bfloat16(f);
  return __builtin_bit_cast(unsigned short, h);
}
DEVINL float bf2f(unsigned short u) {
  unsigned int v = ((unsigned int)u) << 16;
  return __builtin_bit_cast(float, v);
}
DEVINL unsigned cvt_pk_bf16(float lo_, float hi_) {  // (lo,hi) -> packed 2xbf16
  unsigned r;
  asm volatile("v_cvt_pk_bf16_f32 %0, %1, %2" : "=v"(r) : "v"(lo_), "v"(hi_));
  return r;
}
// XOR-swizzled element offset into a [R][128] bf16 LDS tile (16B chunk ^= row&7).
DEVINL int swz(int r, int c) {
  return (r << 7) + ((((c >> 3) ^ (r & 7))) << 3) + (c & 7);
}
// Intra-wave LDS fence (per-wave-private buffers; no cross-wave barrier needed).
DEVINL void wave_sync() {
  asm volatile("s_waitcnt lgkmcnt(0)" ::: "memory");
  __builtin_amdgcn_sched_barrier(0);
}
DEVINL float gelu_f(float x) {  // tanh-approximate gelu (jax default)
  float u = 0.7978845608028654f * (x + 0.044715f * x * x * x);
  float t = 1.0f - 2.0f / (__expf(2.0f * u) + 1.0f);
  return 0.5f * x * (1.0f + t);
}

// Cooperative 16KB weight-half stage (2 kt-slices): global wfrag -> LDS slot.
DEVINL void stage_half(const unsigned short* __restrict__ wf_all,
                       unsigned short* Wslot, int half, int tid) {
  const unsigned short* src = wf_all + (size_t)half * 8192;
  const int wv = tid >> 6, l = tid & 63;
#pragma unroll
  for (int r = 0; r < 4; ++r) {
    int off = (r * 4 + wv) * 512;  // wave-uniform LDS base; HW adds lane*16B
    __builtin_amdgcn_global_load_lds(
        (const __attribute__((address_space(1))) unsigned int*)(src + off + l * 8),
        (__attribute__((address_space(3))) unsigned int*)(Wslot + off),
        16, 0, 0);
  }
}

// ---------------------------------------------------------------------------
// Kernel 0: repack six 128x128 fp32 weights into bf16 MFMA-B-fragment order.
// f = (((kt*8+nt)*64+lane)*8+i) holds W[kt*32+(lane>>4)*8+i][nt*16+(lane&15)]
// ---------------------------------------------------------------------------
__global__ void prep_weights(const float* __restrict__ w0, const float* __restrict__ w1,
                             const float* __restrict__ w2, const float* __restrict__ w3,
                             const float* __restrict__ w4, const float* __restrict__ w5,
                             unsigned short* __restrict__ wfrag) {
  int gid = blockIdx.x * 256 + threadIdx.x;   // < 6*16384
  int widx = gid >> 14, f = gid & 16383;
  const float* W = (widx == 0) ? w0 : (widx == 1) ? w1 : (widx == 2) ? w2
                 : (widx == 3) ? w3 : (widx == 4) ? w4 : w5;
  int i = f & 7, l = (f >> 3) & 63, nt = (f >> 9) & 7, kt = f >> 12;
  int k = kt * 32 + (l >> 4) * 8 + i;
  int n = nt * 16 + (l & 15);
  wfrag[gid] = f2bf(W[k * 128 + n]);
}

// ---------------------------------------------------------------------------
// Kernel 1: kv = LN(x_kv) @ Wkv + bkv  -> bf16 workspace (12288 x 256)
// ---------------------------------------------------------------------------
__global__ __launch_bounds__(256) void kv_proj(
    const float* __restrict__ xkv, const float* __restrict__ lns,
    const float* __restrict__ lnb, const float* __restrict__ Wkv,
    const float* __restrict__ bkv, unsigned short* __restrict__ kvout) {
  __shared__ float y[16][132];
  const int tid = threadIdx.x;
  const size_t rb = (size_t)blockIdx.x * 16;

  {
    int r = tid >> 4, p = tid & 15;
    const float* xr = xkv + (rb + r) * C + p * 8;
    float v[8];
    float sum = 0.f, sq = 0.f;
#pragma unroll
    for (int i = 0; i < 2; ++i) {
      float4 q4 = *(const float4*)(xr + i * 4);
      v[i * 4 + 0] = q4.x; v[i * 4 + 1] = q4.y; v[i * 4 + 2] = q4.z; v[i * 4 + 3] = q4.w;
      sum += q4.x + q4.y + q4.z + q4.w;
      sq  += q4.x * q4.x + q4.y * q4.y + q4.z * q4.z + q4.w * q4.w;
    }
    sum += __shfl_xor(sum, 1, 16); sum += __shfl_xor(sum, 2, 16);
    sum += __shfl_xor(sum, 4, 16); sum += __shfl_xor(sum, 8, 16);
    sq  += __shfl_xor(sq, 1, 16);  sq  += __shfl_xor(sq, 2, 16);
    sq  += __shfl_xor(sq, 4, 16);  sq  += __shfl_xor(sq, 8, 16);
    float mu = sum * (1.0f / 128.f);
    float rs = rsqrtf(sq * (1.0f / 128.f) - mu * mu + 1e-5f);
#pragma unroll
    for (int i = 0; i < 8; ++i) {
      int c = p * 8 + i;
      y[r][c] = (v[i] - mu) * rs * lns[c] + lnb[c];
    }
  }
  __syncthreads();

  const int c2 = tid;
  float acc[16];
#pragma unroll
  for (int r = 0; r < 16; ++r) acc[r] = 0.f;
  for (int c = 0; c < 128; c += 4) {
    float w0 = Wkv[(c + 0) * 256 + c2];
    float w1 = Wkv[(c + 1) * 256 + c2];
    float w2 = Wkv[(c + 2) * 256 + c2];
    float w3 = Wkv[(c + 3) * 256 + c2];
#pragma unroll
    for (int r = 0; r < 16; ++r) {
      float4 yv = *(const float4*)&y[r][c];
      acc[r] += yv.x * w0 + yv.y * w1 + yv.z * w2 + yv.w * w3;
    }
  }
  float bb = bkv[c2];
#pragma unroll
  for (int r = 0; r < 16; ++r)
    kvout[(rb + r) * 256 + c2] = f2bf(acc[r] + bb);
}

// ---------------------------------------------------------------------------
// mm16: per-wave 16x128 @ 128x128. Weights from Wb half ping-pong; stage of
// half j+1 issued at start of half j; one __syncthreads per half (12 total).
// MODE 0: dst=bf16(acc+bias). 1: +gelu. 4: dst=bf16(acc*qk_scale).
// MODE 2: dst=bf16(xq + gamma*(acc+bias))   (x2 build)
// MODE 3: out = x2(xK) + gmlp*(acc+bias) -> global scalar stores.
// ---------------------------------------------------------------------------
template <int MODE>
DEVINL void mm16(const unsigned short* src, unsigned short* dst,
                 unsigned short (*Wb)[8192],
                 const unsigned short* __restrict__ wf_all, int j0,
                 const float* __restrict__ bias,
                 const float* __restrict__ xqw, const float* __restrict__ gamma,
                 const unsigned short* xK, const float* __restrict__ gmlp,
                 float* __restrict__ outw, int tid) {
  const int l = tid & 63, lo = l & 15, g = l >> 4;
  f32x4 acc[8];
#pragma unroll
  for (int nt = 0; nt < 8; ++nt) acc[nt] = f32x4_zero();

#pragma unroll
  for (int hh = 0; hh < 2; ++hh) {
    const int j = j0 + hh;
    if (j + 1 < 12) stage_half(wf_all, Wb[(j + 1) & 1], j + 1, tid);
    const unsigned short* W = Wb[j & 1];
#pragma unroll
    for (int k2 = 0; k2 < 2; ++k2) {
      int kt = hh * 2 + k2;
      bf16x8 a = *(const bf16x8*)(src + swz(lo, kt * 32 + g * 8));
#pragma unroll
      for (int nt = 0; nt < 8; ++nt) {
        bf16x8 b = *(const bf16x8*)(W + (k2 * 8 + nt) * 512 + l * 8);
        acc[nt] = mfma16(a, b, acc[nt]);
      }
    }
    __syncthreads();   // all waves done with W[j&1]; stage j+1 drained
  }

#pragma unroll
  for (int nt = 0; nt < 8; ++nt) {
    int col = nt * 16 + lo;
    float bv = (MODE == 4) ? 0.0f : bias[col];
    float gm = (MODE == 2) ? gamma[col] : 0.0f;
    float gp = (MODE == 3) ? gmlp[col] : 0.0f;
#pragma unroll
    for (int e = 0; e < 4; ++e) {
      int row = g * 4 + e;   // C/D: col=lane&15, row=(lane>>4)*4+e
      float v = acc[nt][e] + bv;
      if (MODE == 1) v = gelu_f(v);
      if (MODE == 4) v = acc[nt][e] * 0.17677669529663687f;  // 1/sqrt(32)
      if (MODE == 2) v = xqw[row * C + col] + gm * v;
      if (MODE == 3) {
        float x2 = bf2f(xK[swz(row, col)]);
        outw[row * C + col] = x2 + gp * v;
      } else {
        dst[swz(row, col)] = f2bf(v);
      }
    }
  }
}

// ---------------------------------------------------------------------------
// Kernel 2: fused main. Block = 4 waves; wave = 1 s-unit (16 q-rows).
// Attention fully on MFMA: St = mfma(K, qh) (transposed scores), softmax via
// 2 shfl_xor, P assembled in-register (12 shfl + cvt_pk), PV = mfma(P, V)
// with V stored n-pair-interleaved in LDS.
// ---------------------------------------------------------------------------
__global__ __launch_bounds__(256, 2) void fused_main(
    const float* __restrict__ xq, const int* __restrict__ nh_idx,
    const unsigned char* __restrict__ nh_mask,
    const unsigned short* __restrict__ wfrag,
    const unsigned short* __restrict__ kvws,
    const float* __restrict__ ln_q_s, const float* __restrict__ ln_q_b,
    const float* __restrict__ bq, const float* __restrict__ b_out,
    const float* __restrict__ gamma, const float* __restrict__ ln_m_s,
    const float* __restrict__ ln_m_b, const float* __restrict__ bm,
    const float* __restrict__ b1, const float* __restrict__ b2,
    const float* __restrict__ gmlp, float* __restrict__ out) {
  __shared__ __align__(16) unsigned short Wb[2][8192];   // 32 KB weight halves
  __shared__ __align__(16) unsigned short SU[4][5248];   // per-su: X|K|Vt

  const int tid = threadIdx.x, l = tid & 63, wv = tid >> 6;
  const int lo = l & 15, g = l >> 4;
  const int bid = blockIdx.x;
  const int t = bid / (SS / 4);
  const int s = (bid % (SS / 4)) * 4 + wv;
  const float* xqw = xq + (size_t)(t * SS + s) * NPQ * C;
  float* outw = out + (size_t)(t * SS + s) * NPQ * C;
  unsigned short* X  = SU[wv];          // 2048: activations [16][128] swz
  unsigned short* K  = SU[wv] + 2048;   // 1152: K rows [9][128] swz
  unsigned short* VT = SU[wv] + 3200;   // 2048: V [8 nt][8 npair][16 d][2]; later x2

  // ---- P0: stage weight half 0; per-lane score bias; issue kv gather
  stage_half(wfrag, Wb[0], 0, tid);
  float sbias[4];
#pragma unroll
  for (int e = 0; e < 4; ++e) {
    int n = g * 4 + e;
    sbias[e] = (n < 9) ? (nh_mask[s * 9 + n] ? 0.0f : -1e9f) : -1e9f;
  }
  uint4 gr[5];
  {
    // idx = i*64 + l; ch = l&31 (const/lane), n = i*2 + (l>>5)
    int ch = l & 31;
#pragma unroll
    for (int i = 0; i < 5; ++i) {
      int idx = i * 64 + l;
      if (idx < 288) {
        int n = i * 2 + (l >> 5);
        int jrow = nh_idx[s * 9 + n];
        gr[i] = *(const uint4*)(kvws + ((size_t)(t * SS + jrow)) * 256 + ch * 8);
      }
    }
  }
  // ---- zero VT (V rows 9..15 must be 0; valid slots overwritten below)
  {
    uint4 z; z.x = 0u; z.y = 0u; z.z = 0u; z.w = 0u;
#pragma unroll
    for (int r = 0; r < 4; ++r)
      *(uint4*)(VT + (r * 64 + l) * 8) = z;
  }
  wave_sync();

  // ---- P1: LN1 of own 16 rows -> X. 4 lanes/row, 32 channels each.
  {
    int r = l >> 2, p = l & 3;
    const float* xr = xqw + r * C + p * 32;
    float v[32];
    float sum = 0.f, sq = 0.f;
#pragma unroll
    for (int i = 0; i < 8; ++i) {
      float4 q4 = *(const float4*)(xr + i * 4);
      v[i * 4 + 0] = q4.x; v[i * 4 + 1] = q4.y; v[i * 4 + 2] = q4.z; v[i * 4 + 3] = q4.w;
      sum += q4.x + q4.y + q4.z + q4.w;
      sq  += q4.x * q4.x + q4.y * q4.y + q4.z * q4.z + q4.w * q4.w;
    }
    sum += __shfl_xor(sum, 1, 4); sum += __shfl_xor(sum, 2, 4);
    sq  += __shfl_xor(sq, 1, 4);  sq  += __shfl_xor(sq, 2, 4);
    float mu = sum * (1.0f / C);
    float rs = rsqrtf(sq * (1.0f / C) - mu * mu + 1e-5f);
#pragma unroll
    for (int cc = 0; cc < 4; ++cc) {
      unsigned short pk[8];
#pragma unroll
      for (int i = 0; i < 8; ++i) {
        int c = p * 32 + cc * 8 + i;
        pk[i] = f2bf((v[cc * 8 + i] - mu) * rs * ln_q_s[c] + ln_q_b[c]);
      }
      *(uint4*)&X[swz(r, p * 32 + cc * 8)] = *(const uint4*)pk;
    }
  }
  // ---- P1.5: land the kv gather. K rows: swizzled b128. V: n-pair interleave.
  {
    int ch = l & 31;
#pragma unroll
    for (int i = 0; i < 5; ++i) {
      int idx = i * 64 + l;
      if (idx < 288) {
        int n = i * 2 + (l >> 5);
        if (ch < 16) {
          *(uint4*)(K + n * 128 + ((ch ^ (n & 7)) << 3)) = gr[i];
        } else {
          int d0 = (ch - 16) * 8;
          int nt = d0 >> 4;
          int base = nt * 256 + (n >> 1) * 32 + (d0 & 15) * 2 + (n & 1);
          const unsigned short* u = (const unsigned short*)&gr[i];
#pragma unroll
          for (int dd = 0; dd < 8; ++dd) VT[base + dd * 2] = u[dd];
        }
      }
    }
  }
  wave_sync();
  __syncthreads();   // Wb[0] staged; everyone ready

  // q  = y1 @ Wq + bq                (X->X), halves 0,1
  mm16<0>(X, X, Wb, wfrag, 0, bq, nullptr, nullptr, nullptr, nullptr, nullptr, tid);
  wave_sync();
  // qh = (q @ Wa_q) * 1/sqrt(hd)     (X->X), halves 2,3
  mm16<4>(X, X, Wb, wfrag, 2, nullptr, nullptr, nullptr, nullptr, nullptr, nullptr, tid);
  wave_sync();

  // ---- attention (wave-local, MFMA)
  {
    const int krow = (lo > 8) ? 8 : lo;   // clamp: finite garbage, killed by bias
    f32x4 st[4];
#pragma unroll
    for (int h = 0; h < 4; ++h) {
      bf16x8 ka = *(const bf16x8*)(K + swz(krow, h * 32 + g * 8));  // A = K
      bf16x8 qb = *(const bf16x8*)(X + swz(lo,   h * 32 + g * 8));  // B = qh
      st[h] = mfma16(ka, qb, f32x4_zero());                         // St[n][q]
    }
    // per head: bias, softmax over n (in-lane e + shfl over g), P A-frag
    bf16x8 pfrag[4];
#pragma unroll
    for (int h = 0; h < 4; ++h) {
      float p0 = st[h][0] + sbias[0], p1 = st[h][1] + sbias[1];
      float p2 = st[h][2] + sbias[2], p3 = st[h][3] + sbias[3];
      float m = fmaxf(fmaxf(p0, p1), fmaxf(p2, p3));
      m = fmaxf(m, __shfl_xor(m, 16));
      m = fmaxf(m, __shfl_xor(m, 32));
      p0 = __expf(p0 - m); p1 = __expf(p1 - m);
      p2 = __expf(p2 - m); p3 = __expf(p3 - m);
      float ss = p0 + p1 + p2 + p3;
      ss += __shfl_xor(ss, 16);
      ss += __shfl_xor(ss, 32);
      float inv = 1.0f / ss;
      p0 *= inv; p1 *= inv; p2 *= inv; p3 *= inv;
      // assemble A-frag: lane needs P[q=lo][n=g*8+i].
      // own lane holds P[n=g*4+e][q=lo]; partners via xor 16/32/48.
      float b0 = __shfl_xor(p0, 16), b1 = __shfl_xor(p1, 16),
            b2 = __shfl_xor(p2, 16), b3 = __shfl_xor(p3, 16);
      float c0 = __shfl_xor(p0, 32), c1 = __shfl_xor(p1, 32),
            c2 = __shfl_xor(p2, 32), c3 = __shfl_xor(p3, 32);
      float d0 = __shfl_xor(p0, 48), d1 = __shfl_xor(p1, 48),
            d2 = __shfl_xor(p2, 48), d3 = __shfl_xor(p3, 48);
      float L0 = (g == 0) ? p0 : (g == 1) ? d0 : 0.f;
      float L1 = (g == 0) ? p1 : (g == 1) ? d1 : 0.f;
      float L2 = (g == 0) ? p2 : (g == 1) ? d2 : 0.f;
      float L3 = (g == 0) ? p3 : (g == 1) ? d3 : 0.f;
      float H0 = (g == 0) ? b0 : (g == 1) ? c0 : 0.f;
      float H1 = (g == 0) ? b1 : (g == 1) ? c1 : 0.f;
      float H2 = (g == 0) ? b2 : (g == 1) ? c2 : 0.f;
      float H3 = (g == 0) ? b3 : (g == 1) ? c3 : 0.f;
      unsigned dw0 = cvt_pk_bf16(L0, L1), dw1 = cvt_pk_bf16(L2, L3);
      unsigned dw2 = cvt_pk_bf16(H0, H1), dw3 = cvt_pk_bf16(H2, H3);
      uint4 pu; pu.x = dw0; pu.y = dw1; pu.z = dw2; pu.w = dw3;
      pfrag[h] = __builtin_bit_cast(bf16x8, pu);
    }
    // PV: out[q][d] = P @ V, 8 d-tiles; B-frag = 4x ds_read_b32 (g<2)
    f32x4 oacc[8];
#pragma unroll
    for (int nt = 0; nt < 8; ++nt) {
      unsigned vw0 = 0, vw1 = 0, vw2 = 0, vw3 = 0;
      if (g < 2) {
        const unsigned short* vb = VT + nt * 256 + g * 128 + lo * 2;
        vw0 = *(const unsigned*)(vb);
        vw1 = *(const unsigned*)(vb + 32);
        vw2 = *(const unsigned*)(vb + 64);
        vw3 = *(const unsigned*)(vb + 96);
      }
      uint4 vu; vu.x = vw0; vu.y = vw1; vu.z = vw2; vu.w = vw3;
      bf16x8 vfrag = __builtin_bit_cast(bf16x8, vu);
      oacc[nt] = mfma16(pfrag[nt >> 1], vfrag, f32x4_zero());
    }
    wave_sync();   // all QK/PV LDS reads done before overwriting X
#pragma unroll
    for (int nt = 0; nt < 8; ++nt)
#pragma unroll
      for (int e = 0; e < 4; ++e)
        X[swz(g * 4 + e, nt * 16 + lo)] = f2bf(oacc[nt][e]);
  }
  wave_sync();

  // x2 = xq + gamma*(ao @ W_out + b_out)   (X->VT; V data dead), halves 4,5
  mm16<2>(X, VT, Wb, wfrag, 4, b_out, xqw, gamma, nullptr, nullptr, nullptr, tid);
  wave_sync();

  // ---- LN2: VT (x2 bf16) -> X (y2); VT keeps x2 for the final epilogue
  {
    int r = l >> 2, p = l & 3;
    float v[32];
    float sum = 0.f, sq = 0.f;
#pragma unroll
    for (int cc = 0; cc < 4; ++cc) {
      uint4 u = *(const uint4*)(VT + swz(r, p * 32 + cc * 8));
      const unsigned short* up = (const unsigned short*)&u;
#pragma unroll
      for (int i = 0; i < 8; ++i) {
        float xv = bf2f(up[i]);
        v[cc * 8 + i] = xv;
        sum += xv; sq += xv * xv;
      }
    }
    sum += __shfl_xor(sum, 1, 4); sum += __shfl_xor(sum, 2, 4);
    sq  += __shfl_xor(sq, 1, 4);  sq  += __shfl_xor(sq, 2, 4);
    float mu = sum * (1.0f / C);
    float rs = rsqrtf(sq * (1.0f / C) - mu * mu + 1e-5f);
#pragma unroll
    for (int cc = 0; cc < 4; ++cc) {
      unsigned short pk[8];
#pragma unroll
      for (int i = 0; i < 8; ++i) {
        int c = p * 32 + cc * 8 + i;
        pk[i] = f2bf((v[cc * 8 + i] - mu) * rs * ln_m_s[c] + ln_m_b[c]);
      }
      *(uint4*)&X[swz(r, p * 32 + cc * 8)] = *(const uint4*)pk;
    }
  }
  wave_sync();

  // h1 = y2 @ Wm + bm        (X->X), halves 6,7
  mm16<0>(X, X, Wb, wfrag, 6, bm, nullptr, nullptr, nullptr, nullptr, nullptr, tid);
  wave_sync();
  // gl = gelu(h1 @ W1 + b1)  (X->X), halves 8,9
  mm16<1>(X, X, Wb, wfrag, 8, b1, nullptr, nullptr, nullptr, nullptr, nullptr, tid);
  wave_sync();
  // m = gl @ W2 + b2; out = x2 + gmlp*m   (X->global), halves 10,11
  mm16<3>(X, nullptr, Wb, wfrag, 10, b2, nullptr, nullptr, VT, gmlp, outw, tid);
}

// ---------------------------------------------------------------------------
extern "C" void kernel_launch(void* const* d_in, const int* in_sizes, int n_in,
                              void* d_out, int out_size, void* d_ws, size_t ws_size,
                              hipStream_t stream) {
  const float* x_q     = (const float*)d_in[0];
  const float* x_kv    = (const float*)d_in[1];
  const int* nh_idx    = (const int*)d_in[2];
  const unsigned char* nh_mask = (const unsigned char*)d_in[3];
  const float* ln_q_s  = (const float*)d_in[4];
  const float* ln_q_b  = (const float*)d_in[5];
  const float* Wq      = (const float*)d_in[6];
  const float* bq      = (const float*)d_in[7];
  const float* ln_kv_s = (const float*)d_in[8];
  const float* ln_kv_b = (const float*)d_in[9];
  const float* Wkv     = (const float*)d_in[10];
  const float* bkv     = (const float*)d_in[11];
  const float* Wa_q    = (const float*)d_in[12];
  const float* W_out   = (const float*)d_in[13];
  const float* b_out   = (const float*)d_in[14];
  const float* gamma   = (const float*)d_in[15];
  const float* ln_m_s  = (const float*)d_in[16];
  const float* ln_m_b  = (const float*)d_in[17];
  const float* Wm      = (const float*)d_in[18];
  const float* bm      = (const float*)d_in[19];
  const float* W1      = (const float*)d_in[20];
  const float* b1      = (const float*)d_in[21];
  const float* W2      = (const float*)d_in[22];
  const float* b2      = (const float*)d_in[23];
  const float* gmlp    = (const float*)d_in[24];

  unsigned short* wfrag = (unsigned short*)d_ws;          // 192 KB
  unsigned short* kvws  = wfrag + 6 * 16384;              // 12.6 MB

  prep_weights<<<384, 256, 0, stream>>>(Wq, Wa_q, W_out, Wm, W1, W2, wfrag);
  kv_proj<<<1536, 256, 0, stream>>>(x_kv, ln_kv_s, ln_kv_b, Wkv, bkv, kvws);
  fused_main<<<6144, 256, 0, stream>>>(x_q, nh_idx, nh_mask, wfrag, kvws,
                                       ln_q_s, ln_q_b, bq, b_out, gamma,
                                       ln_m_s, ln_m_b, bm, b1, b2, gmlp,
                                       (float*)d_out);
}